// Round 6
// baseline (396.796 us; speedup 1.0000x reference)
//
#include <hip/hip_runtime.h>
#include <hip/hip_fp16.h>

// PhiSoftMax: fused causal attention + Gumbel-sigmoid DAG mask, MI355X gfx950.
// B=2, L=S=2048, H=8, E=64.
// Requires ws_size >= 80 MB (packed q/k/v bf16 + partials + bitmask + dg tiles).
//
// R6: split the DAG-mask computation out of the latency-critical kernel.
// Evidence (R0/R2/R4/R5 invariants): attn wave-iter issues ~4.4k cy of VALU
// (transcendentals + softmax + staging addr math) at only 1.45-2 waves/SIMD
// -> ~30us VALU floor plus unhidden latency = 116us, regardless of staging
// structure. Fix: dg_gen streams phi/u once (BW-bound, fully parallel, fp16
// output in exact MFMA fragment order, dead-mask folded in); attn_main loses
// DMA/LDS-stage/dmask/transcendentals (issue/iter ~4.4k -> ~2.5k cy), drops
// register peak (per-batch K/V/Q loads) and runs 3 waves/SIMD (launch_bounds
// (256,3)) so remaining latency overlaps across waves.

#define Bz 2
#define Lz 2048
#define Sz 2048
#define Hz 8
#define Ez 64
#define NSEG 4
#define NEG_BIG (-1e30f)

typedef __attribute__((ext_vector_type(8))) short short8;   // 8 bf16 (4 VGPRs)
typedef __attribute__((ext_vector_type(4))) short short4v;  // 4 bf16 (8B)
typedef __attribute__((ext_vector_type(4))) float f32x4;    // MFMA C/D frag / float4

__device__ __forceinline__ float fast_rcp(float x) { return __builtin_amdgcn_rcpf(x); }

// float -> bf16 bits, round-to-nearest-even (finite inputs only)
__device__ __forceinline__ short f2bf(float x) {
    unsigned bits = __builtin_bit_cast(unsigned, x);
    bits += 0x7FFFu + ((bits >> 16) & 1u);
    return (short)(bits >> 16);
}

// triangle-packed tile prefix: tiles in rows 0..lt-1 (16-row granularity, 64-col tiles)
__device__ __forceinline__ int tri_prefix(int lt) {
    const int m = lt >> 2;
    return lt + 2*m*(m-1) + (lt & 3)*m;
}

// ---------------- prepack: Q (scaled by 1/8) and K to bf16 [b,h,l,e] ----------------
// Also packs the combined dead-mask (hm==0 || causal&&(s>l)) into 1 bit per (l,s):
// dmask[l*32 + s/64], bit (s&63). 512KB total -> L2-resident for dg_gen.
__global__ void pack_qk(const float* __restrict__ q, const float* __restrict__ k,
                        short* __restrict__ qp, short* __restrict__ kp,
                        const int* __restrict__ hm, const int* __restrict__ caus_p,
                        unsigned long long* __restrict__ dmask)
{
    const int t = blockIdx.x * 256 + threadIdx.x;   // 524288 float4 slots
    const float4 qv = ((const float4*)q)[t];
    const float4 kv = ((const float4*)k)[t];
    // flat in-index = ((b*L + l)*H + h)*E + e4*4
    const int e4   = t & 15;
    const int rest = t >> 4;          // (b*L + l)*H + h
    const int h    = rest & 7;
    const int bl   = rest >> 3;       // b*L + l
    const int b    = bl >> 11;
    const int l    = bl & 2047;
    const int o    = ((b*Hz + h)*Lz + l)*Ez + e4*4;
    short4v qo, ko;
    qo[0] = f2bf(qv.x*0.125f); qo[1] = f2bf(qv.y*0.125f);
    qo[2] = f2bf(qv.z*0.125f); qo[3] = f2bf(qv.w*0.125f);
    ko[0] = f2bf(kv.x); ko[1] = f2bf(kv.y); ko[2] = f2bf(kv.z); ko[3] = f2bf(kv.w);
    *(short4v*)&qp[o] = qo;
    *(short4v*)&kp[o] = ko;

    // ---- dead-mask pack: one l-row per block, 8 of 32 words per wave ----
    {
        const int lane = threadIdx.x & 63;
        const int lrow = blockIdx.x;                    // 2048 rows
        const int w0   = (threadIdx.x >> 6) * 8;        // wave's word range
        const int causal = *caus_p;
#pragma unroll
        for (int i = 0; i < 8; ++i) {
            const int tt = w0 + i;
            int dead;
            if (causal && (tt*64 > lrow)) {
                dead = 1;                       // whole word above diagonal: skip hm read
            } else {
                const int s = tt*64 + lane;
                dead = (hm[lrow*Sz + s] == 0) || (causal && (s > lrow));
            }
            const unsigned long long m = __ballot(dead);   // bit i = lane i = s%64
            if (lane == 0) dmask[lrow*32 + tt] = m;
        }
    }
}

// ---------------- prepack: V transposed to bf16 [b,h,e,s] ----------------
__global__ void pack_vt(const float* __restrict__ v, short* __restrict__ vt)
{
    // 1024 blocks: (b, h, s-tile of 32); 256 threads: (sc 0..3, e 0..63)
    const int blk = blockIdx.x;
    const int st  = blk & 63;
    const int h   = (blk >> 6) & 7;
    const int b   = blk >> 9;
    const int s0  = st * 32;
    const int e   = threadIdx.x & 63;
    const int sc  = threadIdx.x >> 6;
    short8 ov;
#pragma unroll
    for (int j = 0; j < 8; ++j) {
        const int s = s0 + sc*8 + j;
        ov[j] = f2bf(v[((b*Sz + s)*Hz + h)*Ez + e]);   // lanes read 256B contiguous per j
    }
    *(short8*)&vt[((b*Hz + h)*Ez + e)*Sz + s0 + sc*8] = ov;
}

// ---------------- dg_gen: stream phi/u -> fp16 DAG penalty tiles ----------------
// Per tile (16 l-rows x 64 s-cols): 64 lanes x 16 fp16 (32B contiguous per lane),
// value v = r*4 + nt at (row quad*4+r, col nt*16+ln) for consumer lane quad*16+ln.
// Dead (hm==0 || s>l) folded in as fp16 -inf. Triangle-packed: 34MB, L3-resident.
__global__ __launch_bounds__(256) void dg_gen(
    const float* __restrict__ phi, const float* __restrict__ u,
    const unsigned long long* __restrict__ dmask, const int* __restrict__ caus_p,
    const float* __restrict__ log_tau_p, const float* __restrict__ thr_p,
    unsigned short* __restrict__ dgp)
{
    const int lane  = threadIdx.x & 63;
    const int wslot = threadIdx.x >> 6;
    const int h     = blockIdx.x & 7;
    const int lt    = 127 - (blockIdx.x >> 3);    // 16-row slice; big rows first
    const int quad  = lane >> 4;
    const int ln    = lane & 15;

    const int causal = *caus_p;
    float tau = __expf(*log_tau_p);
    tau = fminf(fmaxf(tau, 0.1f), 5.0f);
    const float inv_tau = 1.0f / tau;
    const float thr = fminf(fmaxf(*thr_p, 0.01f), 0.99f);

    const int C  = lt >> 2;
    const int Tg = causal ? (C + 1) : (Sz >> 6);
    const int tb = causal ? (h*2112 + tri_prefix(lt)) : (h*128 + lt)*32;

    __shared__ float myd_all[4][16*68];           // +4-dword row pad: conflict-free-ish
    float* myd = myd_all[wslot];

    for (int t = wslot; t < Tg; t += 4) {
        // load layout: lane covers rows quad*4+i, cols ln*4..+3 (256B/row-group)
        unsigned long long dmc[4];
        f32x4 pv[4], uv[4];
#pragma unroll
        for (int i = 0; i < 4; ++i) {
            const int l = lt*16 + quad*4 + i;
            const size_t off = ((size_t)(h*Lz + l))*Sz + (size_t)(t*64 + ln*4);
            pv[i]  = *(const f32x4*)&phi[off];
            uv[i]  = *(const f32x4*)&u[off];
            dmc[i] = dmask[l*32 + t];
        }
#pragma unroll
        for (int i = 0; i < 4; ++i) {
            f32x4 dv;
#pragma unroll
            for (int cc = 0; cc < 4; ++cc) {
                const float uvv = uv[i][cc];
                const float g   = __logf((uvv + 1e-8f) * fast_rcp(1.0f - uvv + 1e-8f));
                const float z   = (g + pv[i][cc]) * inv_tau;
                const float sg  = fast_rcp(1.0f + __expf(-z));
                const float d   = 1250.0f * fminf(sg - thr, 0.0f);   // scale*1e4 folded
                const bool dead = (dmc[i] >> (ln*4 + cc)) & 1ull;
                dv[cc] = dead ? -INFINITY : d;
            }
            *(f32x4*)&myd[(quad*4 + i)*68 + ln*4] = dv;
        }
        asm volatile("s_waitcnt lgkmcnt(0)" ::: "memory");
        __builtin_amdgcn_sched_barrier(0);

        // repack to fragment layout (2-way banks: free), cvt fp16, 32B/lane store
        unsigned out[8];
#pragma unroll
        for (int r = 0; r < 4; ++r) {
            const float v0 = myd[(quad*4 + r)*68 +  0 + ln];
            const float v1 = myd[(quad*4 + r)*68 + 16 + ln];
            const float v2 = myd[(quad*4 + r)*68 + 32 + ln];
            const float v3 = myd[(quad*4 + r)*68 + 48 + ln];
            out[r*2]   = (unsigned)__half_as_ushort(__float2half(v0))
                       | ((unsigned)__half_as_ushort(__float2half(v1)) << 16);
            out[r*2+1] = (unsigned)__half_as_ushort(__float2half(v2))
                       | ((unsigned)__half_as_ushort(__float2half(v3)) << 16);
        }
        const size_t o16 = ((size_t)(tb + t) << 10) + (size_t)lane*16;
        uint4 w0, w1;
        w0.x = out[0]; w0.y = out[1]; w0.z = out[2]; w0.w = out[3];
        w1.x = out[4]; w1.y = out[5]; w1.z = out[6]; w1.w = out[7];
        *(uint4*)&dgp[o16]     = w0;
        *(uint4*)&dgp[o16 + 8] = w1;
    }
}

// ---------------- main: lean flash attention, 4-way S-split ----------------
// Block = (h, 64-row chunk C, seg); 4 waves = row-slices of 16, lockstep tiles.
__global__ __launch_bounds__(256, 3) void attn_main(
    const unsigned short* __restrict__ dgp, const int* __restrict__ causal_p,
    const short* __restrict__ qp, const short* __restrict__ kp,
    const short* __restrict__ vt,
    float* __restrict__ Op, float* __restrict__ Mp, float* __restrict__ Lp)
{
    const int lane  = threadIdx.x & 63;
    const int wslot = threadIdx.x >> 6;
    const int qq    = blockIdx.x;                 // 0..1023
    const int seg   = qq & 3;                     // S-split segment (per block)
    const int cc    = qq >> 2;                    // 0..255 = (chunk, head)
    const int h     = cc & 7;
    const int C     = 31 - (cc >> 3);             // 64-row chunk; big chunks first
    const int l_base = C*64 + wslot*16;           // this wave's 16 rows
    const int ln    = lane & 15;
    const int quad  = lane >> 4;

    const int causal = *causal_p;
    const int lt = C*4 + wslot;
    const int tb = causal ? (h*2112 + tri_prefix(lt)) : (h*128 + lt)*32;
    const int T  = causal ? (C + 1) : (Sz >> 6);

    f32x4 O[2][4];
    float m_r[2][4], l_r[2][4];
#pragma unroll
    for (int b = 0; b < 2; ++b) {
#pragma unroll
        for (int ne = 0; ne < 4; ++ne) { f32x4 z = {0.f,0.f,0.f,0.f}; O[b][ne] = z; }
#pragma unroll
        for (int r = 0; r < 4; ++r) { m_r[b][r] = -INFINITY; l_r[b][r] = 0.f; }
    }

    // per-wave LDS: P scratch only (16x72 halves)
    __shared__ __align__(16) short plds[4][16*72];
    short* myp = &plds[wslot][0];

    for (int t = seg; t < T; t += NSEG) {
        const int s0 = t << 6;

        // dg tile: 32B/lane, fragment order, L2/L3-hot (written by dg_gen)
        const size_t doff = ((size_t)(tb + t) << 10) + (size_t)lane*16;
        const uint4 dA = *(const uint4*)&dgp[doff];
        const uint4 dB = *(const uint4*)&dgp[doff + 8];

        float dgf[4][4];   // [nt][r]

#pragma unroll
        for (int b = 0; b < 2; ++b) {
            // per-batch loads (short liveness keeps regs under the (256,3) cap)
            short8 qfb[2];
#pragma unroll
            for (int k = 0; k < 2; ++k)
                qfb[k] = *(const short8*)&qp[((b*Hz + h)*Lz + l_base + ln)*Ez + k*32 + quad*8];
            short8 kf[4][2];    // B-layout: B[k=quad*8+j][n=ln]
#pragma unroll
            for (int nt = 0; nt < 4; ++nt)
#pragma unroll
                for (int k = 0; k < 2; ++k)
                    kf[nt][k] = *(const short8*)&kp[((b*Hz + h)*Sz + s0 + nt*16 + ln)*Ez + k*32 + quad*8];
            short8 vv[4][2];
#pragma unroll
            for (int ne = 0; ne < 4; ++ne) {
                vv[ne][0] = *(const short8*)&vt[((b*Hz + h)*Ez + ne*16 + ln)*Sz + s0 + quad*8];
                vv[ne][1] = *(const short8*)&vt[((b*Hz + h)*Ez + ne*16 + ln)*Sz + s0 + 32 + quad*8];
            }

            if (b == 0) {
                // unpack dg while kf/vv fly (dA oldest: waiting on it keeps them in flight)
#pragma unroll
                for (int r = 0; r < 4; ++r) {
                    const unsigned dw0 = (r < 2) ? (&dA.x)[r*2]     : (&dB.x)[(r-2)*2];
                    const unsigned dw1 = (r < 2) ? (&dA.x)[r*2 + 1] : (&dB.x)[(r-2)*2 + 1];
                    dgf[0][r] = __half2float(__ushort_as_half((unsigned short)(dw0 & 0xffffu)));
                    dgf[1][r] = __half2float(__ushort_as_half((unsigned short)(dw0 >> 16)));
                    dgf[2][r] = __half2float(__ushort_as_half((unsigned short)(dw1 & 0xffffu)));
                    dgf[3][r] = __half2float(__ushort_as_half((unsigned short)(dw1 >> 16)));
                }
            }

            f32x4 Sc[4];
#pragma unroll
            for (int nt = 0; nt < 4; ++nt) {
                f32x4 z4 = {0.f,0.f,0.f,0.f};
                z4 = __builtin_amdgcn_mfma_f32_16x16x32_bf16(qfb[0], kf[nt][0], z4, 0, 0, 0);
                Sc[nt] = __builtin_amdgcn_mfma_f32_16x16x32_bf16(qfb[1], kf[nt][1], z4, 0, 0, 0);
            }

            // logits (Q pre-scaled by 1/8) + row max; dg folded in place
            float mx[4];
#pragma unroll
            for (int r = 0; r < 4; ++r) mx[r] = -INFINITY;
#pragma unroll
            for (int nt = 0; nt < 4; ++nt)
#pragma unroll
                for (int r = 0; r < 4; ++r) {
                    Sc[nt][r] += dgf[nt][r];
                    mx[r] = fmaxf(mx[r], Sc[nt][r]);
                }
#pragma unroll
            for (int r = 0; r < 4; ++r)
#pragma unroll
                for (int o = 1; o < 16; o <<= 1)
                    mx[r] = fmaxf(mx[r], __shfl_xor(mx[r], o, 16));

            float al[4], mn[4];
#pragma unroll
            for (int r = 0; r < 4; ++r) {
                mn[r] = fmaxf(m_r[b][r], mx[r]);
                al[r] = __expf(fmaxf(m_r[b][r], NEG_BIG) - fmaxf(mn[r], NEG_BIG));
                m_r[b][r] = mn[r];
            }

            float ps[4] = {0.f, 0.f, 0.f, 0.f};
#pragma unroll
            for (int nt = 0; nt < 4; ++nt)
#pragma unroll
                for (int r = 0; r < 4; ++r) {
                    const float p = __expf(Sc[nt][r] - fmaxf(mn[r], NEG_BIG));
                    ps[r] += p;
                    myp[(quad*4 + r)*72 + nt*16 + ln] = f2bf(p);   // C-layout -> LDS
                }
#pragma unroll
            for (int r = 0; r < 4; ++r) {
#pragma unroll
                for (int o = 1; o < 16; o <<= 1)
                    ps[r] += __shfl_xor(ps[r], o, 16);
                l_r[b][r] = l_r[b][r] * al[r] + ps[r];
            }
#pragma unroll
            for (int ne = 0; ne < 4; ++ne)
#pragma unroll
                for (int r = 0; r < 4; ++r)
                    O[b][ne][r] *= al[r];

            // P back in A-layout (same wave; compiler inserts lgkmcnt wait)
            short8 pa[2];
#pragma unroll
            for (int k = 0; k < 2; ++k)
                pa[k] = *(const short8*)&myp[ln*72 + k*32 + quad*8];

#pragma unroll
            for (int ne = 0; ne < 4; ++ne) {
                O[b][ne] = __builtin_amdgcn_mfma_f32_16x16x32_bf16(pa[0], vv[ne][0], O[b][ne], 0, 0, 0);
                O[b][ne] = __builtin_amdgcn_mfma_f32_16x16x32_bf16(pa[1], vv[ne][1], O[b][ne], 0, 0, 0);
            }
        }
    }

    // ---- write partials (unnormalized O, running m, running l) ----
#pragma unroll
    for (int b = 0; b < 2; ++b) {
#pragma unroll
        for (int ne = 0; ne < 4; ++ne)
#pragma unroll
            for (int r = 0; r < 4; ++r) {
                const int l = l_base + quad*4 + r;
                Op[(((seg*2 + b)*Hz + h)*Lz + l)*Ez + ne*16 + ln] = O[b][ne][r];
            }
        if (ln == 0) {
#pragma unroll
            for (int r = 0; r < 4; ++r) {
                const int l = l_base + quad*4 + r;
                Mp[((seg*2 + b)*Hz + h)*Lz + l] = m_r[b][r];
                Lp[((seg*2 + b)*Hz + h)*Lz + l] = l_r[b][r];
            }
        }
    }
}

// ---------------- merge the 4 S-split partials, normalize, write [b,l,h,e] ----------------
__global__ void merge_k(const float* __restrict__ Op, const float* __restrict__ Mp,
                        const float* __restrict__ Lp, float* __restrict__ out)
{
    const int t = blockIdx.x * 256 + threadIdx.x;    // 524288 = B*L*H*E/4
    const int e4   = (t & 15) * 4;
    const int rest = t >> 4;
    const int h    = rest & 7;
    const int bl   = rest >> 3;
    const int b    = bl >> 11;
    const int l    = bl & 2047;

    float ms[NSEG], ls[NSEG], m = -INFINITY;
#pragma unroll
    for (int s = 0; s < NSEG; ++s) {
        const int idx = ((s*2 + b)*Hz + h)*Lz + l;
        ms[s] = Mp[idx];
        ls[s] = Lp[idx];
        m = fmaxf(m, ms[s]);
    }
    const float mg = fmaxf(m, NEG_BIG);
    float den = 0.f, a0 = 0.f, a1 = 0.f, a2 = 0.f, a3 = 0.f;
#pragma unroll
    for (int s = 0; s < NSEG; ++s) {
        const float w = __expf(fmaxf(ms[s], NEG_BIG) - mg);
        den += w * ls[s];
        const float4 ov = *(const float4*)&Op[(((s*2 + b)*Hz + h)*Lz + l)*Ez + e4];
        a0 += w * ov.x; a1 += w * ov.y; a2 += w * ov.z; a3 += w * ov.w;
    }
    const float rd = 1.0f / den;   // diagonal is always open -> den > 0
    float4 res;
    res.x = a0 * rd; res.y = a1 * rd; res.z = a2 * rd; res.w = a3 * rd;
    *(float4*)&out[((b*Lz + l)*Hz + h)*Ez + e4] = res;
}

extern "C" void kernel_launch(void* const* d_in, const int* in_sizes, int n_in,
                              void* d_out, int out_size, void* d_ws, size_t ws_size,
                              hipStream_t stream)
{
    const float* q     = (const float*)d_in[0];
    const float* k     = (const float*)d_in[1];
    const float* v     = (const float*)d_in[2];
    // d_in[3], d_in[4]: mask_miss_k/q (unused); d_in[5]: pos (monotone arange, folded into causal logic)
    const int*   caus  = (const int*)d_in[6];
    const int*   hm    = (const int*)d_in[7];
    const float* phi   = (const float*)d_in[8];
    const float* ltau  = (const float*)d_in[9];
    const float* thr   = (const float*)d_in[10];
    const float* u     = (const float*)d_in[11];

    char* ws = (char*)d_ws;
    short* qp = (short*)(ws);                          //  4 MB
    short* kp = (short*)(ws + (size_t)( 4u << 20));    //  4 MB
    short* vt = (short*)(ws + (size_t)( 8u << 20));    //  4 MB
    float* Op = (float*)(ws + (size_t)(12u << 20));    // 32 MB
    float* Mp = (float*)(ws + (size_t)(44u << 20));    // 512 KB
    float* Lp = (float*)(ws + (size_t)(44u << 20) + (512u << 10));   // 512 KB
    unsigned long long* dmask = (unsigned long long*)(ws + (size_t)(45u << 20)); // 512 KB
    unsigned short* dgp = (unsigned short*)(ws + (size_t)(46u << 20));           // 34 MB (triangle)

    pack_qk <<<2048, 256, 0, stream>>>(q, k, qp, kp, hm, caus, dmask);
    pack_vt <<<1024, 256, 0, stream>>>(v, vt);
    dg_gen  <<<1024, 256, 0, stream>>>(phi, u, dmask, caus, ltau, thr, dgp);
    attn_main<<<1024, 256, 0, stream>>>(dgp, caus, qp, kp, vt, Op, Mp, Lp);
    merge_k <<<2048, 256, 0, stream>>>(Op, Mp, Lp, (float*)d_out);
}

// Round 8
// 394.792 us; speedup vs baseline: 1.0051x; 1.0051x over previous
//
#include <hip/hip_runtime.h>
#include <hip/hip_fp16.h>

// PhiSoftMax: fused causal attention + Gumbel-sigmoid DAG mask, MI355X gfx950.
// B=2, L=S=2048, H=8, E=64.
// Requires ws_size >= 80 MB (packed q/k/v bf16 + partials + dg tiles).
//
// R8: R7's in-kernel split-K merge FAILED correctness (absmax 0.39): the merge
// read sibling blocks' partials with plain loads; sibling blocks live on other
// XCDs, whose L2s are not cross-coherent (G16) -> stale partials. __threadfence
// was not sufficient. Reverted to the R6-verified attn_main + merge_k pair
// (kernel boundary provides the coherence). KEPT the prep fusion (pack_qk +
// pack_vt + dg_gen in one region-branched dispatch; hard_mask read inline,
// dmask intermediate deleted): 5 -> 3 dispatches. Tests the dispatch-overhead
// model (total ~= sum(work) + 49us * n_dispatch, fit R0/R5/R6 to ~1%) at n=3.

#define Bz 2
#define Lz 2048
#define Sz 2048
#define Hz 8
#define Ez 64
#define NSEG 4
#define NEG_BIG (-1e30f)

typedef __attribute__((ext_vector_type(8))) short short8;   // 8 bf16 (4 VGPRs)
typedef __attribute__((ext_vector_type(4))) short short4v;  // 4 bf16 (8B)
typedef __attribute__((ext_vector_type(4))) float f32x4;    // MFMA C/D frag / float4

__device__ __forceinline__ float fast_rcp(float x) { return __builtin_amdgcn_rcpf(x); }

// float -> bf16 bits, round-to-nearest-even (finite inputs only)
__device__ __forceinline__ short f2bf(float x) {
    unsigned bits = __builtin_bit_cast(unsigned, x);
    bits += 0x7FFFu + ((bits >> 16) & 1u);
    return (short)(bits >> 16);
}

// triangle-packed tile prefix: tiles in rows 0..lt-1 (16-row granularity, 64-col tiles)
__device__ __forceinline__ int tri_prefix(int lt) {
    const int m = lt >> 2;
    return lt + 2*m*(m-1) + (lt & 3)*m;
}

// ---------------- prep: pack Q/K, pack V^T, dg tiles — one dispatch ----------------
// blocks [0,2048):   Q (x1/8) + K -> bf16 [b,h,l,e]
// blocks [2048,3072): V -> bf16 [b,h,e,s]
// blocks [3072,4096): phi/u + hard_mask -> fp16 DAG penalty tiles (frag order)
__global__ __launch_bounds__(256) void prep(
    const float* __restrict__ q, const float* __restrict__ k,
    const float* __restrict__ v,
    const float* __restrict__ phi, const float* __restrict__ u,
    const int* __restrict__ hm, const int* __restrict__ caus_p,
    const float* __restrict__ log_tau_p, const float* __restrict__ thr_p,
    short* __restrict__ qp, short* __restrict__ kp, short* __restrict__ vt,
    unsigned short* __restrict__ dgp)
{
    const int blk = blockIdx.x;

    if (blk < 2048) {
        // ---------------- Q/K pack ----------------
        const int t = blk * 256 + threadIdx.x;       // 524288 float4 slots
        const float4 qv = ((const float4*)q)[t];
        const float4 kv = ((const float4*)k)[t];
        const int e4   = t & 15;
        const int rest = t >> 4;          // (b*L + l)*H + h
        const int h    = rest & 7;
        const int bl   = rest >> 3;
        const int b    = bl >> 11;
        const int l    = bl & 2047;
        const int o    = ((b*Hz + h)*Lz + l)*Ez + e4*4;
        short4v qo, ko;
        qo[0] = f2bf(qv.x*0.125f); qo[1] = f2bf(qv.y*0.125f);
        qo[2] = f2bf(qv.z*0.125f); qo[3] = f2bf(qv.w*0.125f);
        ko[0] = f2bf(kv.x); ko[1] = f2bf(kv.y); ko[2] = f2bf(kv.z); ko[3] = f2bf(kv.w);
        *(short4v*)&qp[o] = qo;
        *(short4v*)&kp[o] = ko;
        return;
    }

    if (blk < 3072) {
        // ---------------- V^T pack ----------------
        const int bk  = blk - 2048;
        const int st  = bk & 63;
        const int h   = (bk >> 6) & 7;
        const int b   = bk >> 9;
        const int s0  = st * 32;
        const int e   = threadIdx.x & 63;
        const int sc  = threadIdx.x >> 6;
        short8 ov;
#pragma unroll
        for (int j = 0; j < 8; ++j) {
            const int s = s0 + sc*8 + j;
            ov[j] = f2bf(v[((b*Sz + s)*Hz + h)*Ez + e]);
        }
        *(short8*)&vt[((b*Hz + h)*Ez + e)*Sz + s0 + sc*8] = ov;
        return;
    }

    // ---------------- dg tiles: phi/u + hard_mask -> fp16 fragment-order ----------------
    // Per tile (16 l-rows x 64 s-cols): 64 lanes x 16 fp16 (32B/lane), dead folded as -inf.
    {
        const int bk    = blk - 3072;
        const int lane  = threadIdx.x & 63;
        const int wslot = threadIdx.x >> 6;
        const int h     = bk & 7;
        const int lt    = 127 - (bk >> 3);    // 16-row slice; big rows first
        const int quad  = lane >> 4;
        const int ln    = lane & 15;

        const int causal = *caus_p;
        float tau = __expf(*log_tau_p);
        tau = fminf(fmaxf(tau, 0.1f), 5.0f);
        const float inv_tau = 1.0f / tau;
        const float thr = fminf(fmaxf(*thr_p, 0.01f), 0.99f);

        const int C  = lt >> 2;
        const int Tg = causal ? (C + 1) : (Sz >> 6);
        const int tb = causal ? (h*2112 + tri_prefix(lt)) : (h*128 + lt)*32;

        __shared__ float myd_all[4][16*68];           // +4-dword row pad
        float* myd = myd_all[wslot];

        for (int t = wslot; t < Tg; t += 4) {
            f32x4 pv[4], uv[4];
            int4  hm4[4];
#pragma unroll
            for (int i = 0; i < 4; ++i) {
                const int l = lt*16 + quad*4 + i;
                const size_t off = ((size_t)(h*Lz + l))*Sz + (size_t)(t*64 + ln*4);
                pv[i]  = *(const f32x4*)&phi[off];
                uv[i]  = *(const f32x4*)&u[off];
                hm4[i] = *(const int4*)&hm[l*Sz + t*64 + ln*4];
            }
#pragma unroll
            for (int i = 0; i < 4; ++i) {
                const int l = lt*16 + quad*4 + i;
                f32x4 dv;
#pragma unroll
                for (int cc = 0; cc < 4; ++cc) {
                    const float uvv = uv[i][cc];
                    const float g   = __logf((uvv + 1e-8f) * fast_rcp(1.0f - uvv + 1e-8f));
                    const float z   = (g + pv[i][cc]) * inv_tau;
                    const float sg  = fast_rcp(1.0f + __expf(-z));
                    const float d   = 1250.0f * fminf(sg - thr, 0.0f);   // scale*1e4 folded
                    const int s     = t*64 + ln*4 + cc;
                    const int hmv   = (&hm4[i].x)[cc];
                    const bool dead = (hmv == 0) || (causal && (s > l));
                    dv[cc] = dead ? -INFINITY : d;
                }
                *(f32x4*)&myd[(quad*4 + i)*68 + ln*4] = dv;
            }
            asm volatile("s_waitcnt lgkmcnt(0)" ::: "memory");
            __builtin_amdgcn_sched_barrier(0);

            // repack to fragment layout (2-way banks: free), cvt fp16, 32B/lane store
            unsigned out[8];
#pragma unroll
            for (int r = 0; r < 4; ++r) {
                const float v0 = myd[(quad*4 + r)*68 +  0 + ln];
                const float v1 = myd[(quad*4 + r)*68 + 16 + ln];
                const float v2 = myd[(quad*4 + r)*68 + 32 + ln];
                const float v3 = myd[(quad*4 + r)*68 + 48 + ln];
                out[r*2]   = (unsigned)__half_as_ushort(__float2half(v0))
                           | ((unsigned)__half_as_ushort(__float2half(v1)) << 16);
                out[r*2+1] = (unsigned)__half_as_ushort(__float2half(v2))
                           | ((unsigned)__half_as_ushort(__float2half(v3)) << 16);
            }
            const size_t o16 = ((size_t)(tb + t) << 10) + (size_t)lane*16;
            uint4 w0, w1;
            w0.x = out[0]; w0.y = out[1]; w0.z = out[2]; w0.w = out[3];
            w1.x = out[4]; w1.y = out[5]; w1.z = out[6]; w1.w = out[7];
            *(uint4*)&dgp[o16]     = w0;
            *(uint4*)&dgp[o16 + 8] = w1;
        }
    }
}

// ---------------- main: lean flash attention, 4-way S-split (R6-verified) ----------------
// Block = (h, 64-row chunk C, seg); 4 waves = row-slices of 16, lockstep tiles.
__global__ __launch_bounds__(256, 3) void attn_main(
    const unsigned short* __restrict__ dgp, const int* __restrict__ causal_p,
    const short* __restrict__ qp, const short* __restrict__ kp,
    const short* __restrict__ vt,
    float* __restrict__ Op, float* __restrict__ Mp, float* __restrict__ Lp)
{
    const int lane  = threadIdx.x & 63;
    const int wslot = threadIdx.x >> 6;
    const int qq    = blockIdx.x;                 // 0..1023
    const int seg   = qq & 3;                     // S-split segment (per block)
    const int cc    = qq >> 2;                    // 0..255 = (chunk, head)
    const int h     = cc & 7;
    const int C     = 31 - (cc >> 3);             // 64-row chunk; big chunks first
    const int l_base = C*64 + wslot*16;           // this wave's 16 rows
    const int ln    = lane & 15;
    const int quad  = lane >> 4;

    const int causal = *causal_p;
    const int lt = C*4 + wslot;
    const int tb = causal ? (h*2112 + tri_prefix(lt)) : (h*128 + lt)*32;
    const int T  = causal ? (C + 1) : (Sz >> 6);

    f32x4 O[2][4];
    float m_r[2][4], l_r[2][4];
#pragma unroll
    for (int b = 0; b < 2; ++b) {
#pragma unroll
        for (int ne = 0; ne < 4; ++ne) { f32x4 z = {0.f,0.f,0.f,0.f}; O[b][ne] = z; }
#pragma unroll
        for (int r = 0; r < 4; ++r) { m_r[b][r] = -INFINITY; l_r[b][r] = 0.f; }
    }

    // per-wave LDS: P scratch only (16x72 halves)
    __shared__ __align__(16) short plds[4][16*72];
    short* myp = &plds[wslot][0];

    for (int t = seg; t < T; t += NSEG) {
        const int s0 = t << 6;

        // dg tile: 32B/lane, fragment order, L2/L3-hot (written by prep)
        const size_t doff = ((size_t)(tb + t) << 10) + (size_t)lane*16;
        const uint4 dA = *(const uint4*)&dgp[doff];
        const uint4 dB = *(const uint4*)&dgp[doff + 8];

        float dgf[4][4];   // [nt][r]

#pragma unroll
        for (int b = 0; b < 2; ++b) {
            // per-batch loads (short liveness keeps regs under the (256,3) cap)
            short8 qfb[2];
#pragma unroll
            for (int k = 0; k < 2; ++k)
                qfb[k] = *(const short8*)&qp[((b*Hz + h)*Lz + l_base + ln)*Ez + k*32 + quad*8];
            short8 kf[4][2];    // B-layout: B[k=quad*8+j][n=ln]
#pragma unroll
            for (int nt = 0; nt < 4; ++nt)
#pragma unroll
                for (int k = 0; k < 2; ++k)
                    kf[nt][k] = *(const short8*)&kp[((b*Hz + h)*Sz + s0 + nt*16 + ln)*Ez + k*32 + quad*8];
            short8 vv[4][2];
#pragma unroll
            for (int ne = 0; ne < 4; ++ne) {
                vv[ne][0] = *(const short8*)&vt[((b*Hz + h)*Ez + ne*16 + ln)*Sz + s0 + quad*8];
                vv[ne][1] = *(const short8*)&vt[((b*Hz + h)*Ez + ne*16 + ln)*Sz + s0 + 32 + quad*8];
            }

            if (b == 0) {
                // unpack dg while kf/vv fly (dA oldest: waiting on it keeps them in flight)
#pragma unroll
                for (int r = 0; r < 4; ++r) {
                    const unsigned dw0 = (r < 2) ? (&dA.x)[r*2]     : (&dB.x)[(r-2)*2];
                    const unsigned dw1 = (r < 2) ? (&dA.x)[r*2 + 1] : (&dB.x)[(r-2)*2 + 1];
                    dgf[0][r] = __half2float(__ushort_as_half((unsigned short)(dw0 & 0xffffu)));
                    dgf[1][r] = __half2float(__ushort_as_half((unsigned short)(dw0 >> 16)));
                    dgf[2][r] = __half2float(__ushort_as_half((unsigned short)(dw1 & 0xffffu)));
                    dgf[3][r] = __half2float(__ushort_as_half((unsigned short)(dw1 >> 16)));
                }
            }

            f32x4 Sc[4];
#pragma unroll
            for (int nt = 0; nt < 4; ++nt) {
                f32x4 z4 = {0.f,0.f,0.f,0.f};
                z4 = __builtin_amdgcn_mfma_f32_16x16x32_bf16(qfb[0], kf[nt][0], z4, 0, 0, 0);
                Sc[nt] = __builtin_amdgcn_mfma_f32_16x16x32_bf16(qfb[1], kf[nt][1], z4, 0, 0, 0);
            }

            // logits (Q pre-scaled by 1/8) + row max; dg folded in place
            float mx[4];
#pragma unroll
            for (int r = 0; r < 4; ++r) mx[r] = -INFINITY;
#pragma unroll
            for (int nt = 0; nt < 4; ++nt)
#pragma unroll
                for (int r = 0; r < 4; ++r) {
                    Sc[nt][r] += dgf[nt][r];
                    mx[r] = fmaxf(mx[r], Sc[nt][r]);
                }
#pragma unroll
            for (int r = 0; r < 4; ++r)
#pragma unroll
                for (int o = 1; o < 16; o <<= 1)
                    mx[r] = fmaxf(mx[r], __shfl_xor(mx[r], o, 16));

            float al[4], mn[4];
#pragma unroll
            for (int r = 0; r < 4; ++r) {
                mn[r] = fmaxf(m_r[b][r], mx[r]);
                al[r] = __expf(fmaxf(m_r[b][r], NEG_BIG) - fmaxf(mn[r], NEG_BIG));
                m_r[b][r] = mn[r];
            }

            float ps[4] = {0.f, 0.f, 0.f, 0.f};
#pragma unroll
            for (int nt = 0; nt < 4; ++nt)
#pragma unroll
                for (int r = 0; r < 4; ++r) {
                    const float p = __expf(Sc[nt][r] - fmaxf(mn[r], NEG_BIG));
                    ps[r] += p;
                    myp[(quad*4 + r)*72 + nt*16 + ln] = f2bf(p);   // C-layout -> LDS
                }
#pragma unroll
            for (int r = 0; r < 4; ++r) {
#pragma unroll
                for (int o = 1; o < 16; o <<= 1)
                    ps[r] += __shfl_xor(ps[r], o, 16);
                l_r[b][r] = l_r[b][r] * al[r] + ps[r];
            }
#pragma unroll
            for (int ne = 0; ne < 4; ++ne)
#pragma unroll
                for (int r = 0; r < 4; ++r)
                    O[b][ne][r] *= al[r];

            // P back in A-layout (same wave; compiler inserts lgkmcnt wait)
            short8 pa[2];
#pragma unroll
            for (int k = 0; k < 2; ++k)
                pa[k] = *(const short8*)&myp[ln*72 + k*32 + quad*8];

#pragma unroll
            for (int ne = 0; ne < 4; ++ne) {
                O[b][ne] = __builtin_amdgcn_mfma_f32_16x16x32_bf16(pa[0], vv[ne][0], O[b][ne], 0, 0, 0);
                O[b][ne] = __builtin_amdgcn_mfma_f32_16x16x32_bf16(pa[1], vv[ne][1], O[b][ne], 0, 0, 0);
            }
        }
    }

    // ---- write partials (unnormalized O, running m, running l) ----
#pragma unroll
    for (int b = 0; b < 2; ++b) {
#pragma unroll
        for (int ne = 0; ne < 4; ++ne)
#pragma unroll
            for (int r = 0; r < 4; ++r) {
                const int l = l_base + quad*4 + r;
                Op[(((seg*2 + b)*Hz + h)*Lz + l)*Ez + ne*16 + ln] = O[b][ne][r];
            }
        if (ln == 0) {
#pragma unroll
            for (int r = 0; r < 4; ++r) {
                const int l = l_base + quad*4 + r;
                Mp[((seg*2 + b)*Hz + h)*Lz + l] = m_r[b][r];
                Lp[((seg*2 + b)*Hz + h)*Lz + l] = l_r[b][r];
            }
        }
    }
}

// ---------------- merge the 4 S-split partials, normalize, write [b,l,h,e] ----------------
__global__ void merge_k(const float* __restrict__ Op, const float* __restrict__ Mp,
                        const float* __restrict__ Lp, float* __restrict__ out)
{
    const int t = blockIdx.x * 256 + threadIdx.x;    // 524288 = B*L*H*E/4
    const int e4   = (t & 15) * 4;
    const int rest = t >> 4;
    const int h    = rest & 7;
    const int bl   = rest >> 3;
    const int b    = bl >> 11;
    const int l    = bl & 2047;

    float ms[NSEG], ls[NSEG], m = -INFINITY;
#pragma unroll
    for (int s = 0; s < NSEG; ++s) {
        const int idx = ((s*2 + b)*Hz + h)*Lz + l;
        ms[s] = Mp[idx];
        ls[s] = Lp[idx];
        m = fmaxf(m, ms[s]);
    }
    const float mg = fmaxf(m, NEG_BIG);
    float den = 0.f, a0 = 0.f, a1 = 0.f, a2 = 0.f, a3 = 0.f;
#pragma unroll
    for (int s = 0; s < NSEG; ++s) {
        const float w = __expf(fmaxf(ms[s], NEG_BIG) - mg);
        den += w * ls[s];
        const float4 ov = *(const float4*)&Op[(((s*2 + b)*Hz + h)*Lz + l)*Ez + e4];
        a0 += w * ov.x; a1 += w * ov.y; a2 += w * ov.z; a3 += w * ov.w;
    }
    const float rd = 1.0f / den;   // diagonal is always open -> den > 0
    float4 res;
    res.x = a0 * rd; res.y = a1 * rd; res.z = a2 * rd; res.w = a3 * rd;
    *(float4*)&out[((b*Lz + l)*Hz + h)*Ez + e4] = res;
}

extern "C" void kernel_launch(void* const* d_in, const int* in_sizes, int n_in,
                              void* d_out, int out_size, void* d_ws, size_t ws_size,
                              hipStream_t stream)
{
    const float* q     = (const float*)d_in[0];
    const float* k     = (const float*)d_in[1];
    const float* v     = (const float*)d_in[2];
    // d_in[3], d_in[4]: mask_miss_k/q (unused); d_in[5]: pos (monotone arange, folded into causal logic)
    const int*   caus  = (const int*)d_in[6];
    const int*   hm    = (const int*)d_in[7];
    const float* phi   = (const float*)d_in[8];
    const float* ltau  = (const float*)d_in[9];
    const float* thr   = (const float*)d_in[10];
    const float* u     = (const float*)d_in[11];

    char* ws = (char*)d_ws;
    short* qp = (short*)(ws);                          //  4 MB
    short* kp = (short*)(ws + (size_t)( 4u << 20));    //  4 MB
    short* vt = (short*)(ws + (size_t)( 8u << 20));    //  4 MB
    float* Op = (float*)(ws + (size_t)(12u << 20));    // 32 MB
    float* Mp = (float*)(ws + (size_t)(44u << 20));    // 512 KB
    float* Lp = (float*)(ws + (size_t)(44u << 20) + (512u << 10));   // 512 KB
    unsigned short* dgp = (unsigned short*)(ws + (size_t)(46u << 20)); // 34 MB (triangle)

    prep     <<<4096, 256, 0, stream>>>(q, k, v, phi, u, hm, caus, ltau, thr,
                                        qp, kp, vt, dgp);
    attn_main<<<1024, 256, 0, stream>>>(dgp, caus, qp, kp, vt, Op, Mp, Lp);
    merge_k  <<<2048, 256, 0, stream>>>(Op, Mp, Lp, (float*)d_out);
}